// Round 1
// baseline (1764.373 us; speedup 1.0000x reference)
//
#include <hip/hip_runtime.h>

// FBSNN loss, fp32 baseline.
// Layout: grid=64 blocks (64 paths each), block=256 threads = 4 waves.
// lane = path (within block), wave = 16-unit slice of the 64-wide hidden dim.
// Weights are wave-uniform -> scalar (s_load) operands; activations go via LDS.

#define NPATH   4096
#define NSTEP   50
#define DT_F    0.02f
#define SQRT_DT 0.14142136f
#define SIGMA_F 0.5f

// ---------- MLP building blocks ----------

__device__ __forceinline__ void in_layer_fwd(float t, float y,
    const float* __restrict__ Win, const float* __restrict__ bin,
    float* __restrict__ dst, int lane, int ub)
{
#pragma unroll
    for (int i = 0; i < 16; ++i) {
        int u = ub + i;
        float uv = fmaf(t, Win[u], fmaf(y, Win[64 + u], bin[u]));
        dst[u * 64 + lane] = __sinf(uv);
    }
}

__device__ __forceinline__ void in_layer_tan(float t, float y,
    const float* __restrict__ Win, const float* __restrict__ bin,
    float* __restrict__ dst, float* __restrict__ ddst, int lane, int ub)
{
#pragma unroll
    for (int i = 0; i < 16; ++i) {
        int u = ub + i;
        float w1 = Win[64 + u];
        float uv = fmaf(t, Win[u], fmaf(y, w1, bin[u]));
        float s, c;
        __sincosf(uv, &s, &c);
        dst[u * 64 + lane]  = s;
        ddst[u * 64 + lane] = c * w1;   // d/dy of sin(pre-act), seed dy=1
    }
}

__device__ __forceinline__ void hidden_fwd(
    const float* __restrict__ W, const float* __restrict__ b,
    const float* __restrict__ src, float* __restrict__ dst, int lane, int ub)
{
    float acc[16];
#pragma unroll
    for (int i = 0; i < 16; ++i) acc[i] = b[ub + i];
#pragma unroll 4
    for (int k = 0; k < 64; ++k) {
        float hk = src[k * 64 + lane];            // ds_read_b32, coalesced
        const float* wr = W + k * 64 + ub;        // wave-uniform -> s_load
#pragma unroll
        for (int i = 0; i < 16; ++i) acc[i] = fmaf(hk, wr[i], acc[i]);
    }
#pragma unroll
    for (int i = 0; i < 16; ++i) dst[(ub + i) * 64 + lane] = __sinf(acc[i]);
}

__device__ __forceinline__ void hidden_fwd_tan(
    const float* __restrict__ W, const float* __restrict__ b,
    const float* __restrict__ src, const float* __restrict__ dsrc,
    float* __restrict__ dst, float* __restrict__ ddst, int lane, int ub)
{
    float acc[16], dacc[16];
#pragma unroll
    for (int i = 0; i < 16; ++i) { acc[i] = b[ub + i]; dacc[i] = 0.0f; }
#pragma unroll 2
    for (int k = 0; k < 64; ++k) {
        float hk = src[k * 64 + lane];
        float dk = dsrc[k * 64 + lane];
        const float* wr = W + k * 64 + ub;        // same W row feeds both sums
#pragma unroll
        for (int i = 0; i < 16; ++i) {
            float w = wr[i];
            acc[i]  = fmaf(hk, w, acc[i]);
            dacc[i] = fmaf(dk, w, dacc[i]);
        }
    }
#pragma unroll
    for (int i = 0; i < 16; ++i) {
        float s, c;
        __sincosf(acc[i], &s, &c);
        dst[(ub + i) * 64 + lane]  = s;
        ddst[(ub + i) * 64 + lane] = c * dacc[i];
    }
}

__device__ __forceinline__ float out_layer(const float* __restrict__ src,
    const float* __restrict__ W, float bias, int lane)
{
    float acc = bias;
#pragma unroll 4
    for (int k = 0; k < 64; ++k) acc = fmaf(src[k * 64 + lane], W[k], acc);
    return acc;
}

// Y-net forward + tangent. Buffers: in->(A,dA); l0 A->B; l1 B->A; l2 A->B; out reads B.
__device__ __forceinline__ void ynet_eval(float t, float y,
    const float* __restrict__ Win, const float* __restrict__ bin,
    const float* __restrict__ Whid, const float* __restrict__ bhid,
    const float* __restrict__ Wout, float bout_,
    float* sA, float* sB, float* sdA, float* sdB,
    int lane, int ub, float& Yv, float& dYv)
{
    in_layer_tan(t, y, Win, bin, sA, sdA, lane, ub);
    __syncthreads();
    hidden_fwd_tan(Whid,        bhid,       sA, sdA, sB, sdB, lane, ub); __syncthreads();
    hidden_fwd_tan(Whid + 4096, bhid + 64,  sB, sdB, sA, sdA, lane, ub); __syncthreads();
    hidden_fwd_tan(Whid + 8192, bhid + 128, sA, sdA, sB, sdB, lane, ub); __syncthreads();
    Yv  = out_layer(sB,  Wout, bout_, lane);
    dYv = out_layer(sdB, Wout, 0.0f,  lane);
}

// ---------- main kernel ----------

extern "C" __global__ void __launch_bounds__(256)
fbsnn_kernel(const float* __restrict__ Y_Win, const float* __restrict__ Y_bin,
             const float* __restrict__ Y_Whid, const float* __restrict__ Y_bhid,
             const float* __restrict__ Y_Wout, const float* __restrict__ Y_bout,
             const float* __restrict__ q_Win, const float* __restrict__ q_bin,
             const float* __restrict__ q_Whid, const float* __restrict__ q_bhid,
             const float* __restrict__ q_Wout, const float* __restrict__ q_bout,
             const float* __restrict__ y0p, const float* __restrict__ dW,
             float* __restrict__ out)
{
    __shared__ float sA[4096];
    __shared__ float sB[4096];
    __shared__ float sdA[4096];
    __shared__ float sdB[4096];

    const int lane = (int)(threadIdx.x & 63);
    const int ub   = __builtin_amdgcn_readfirstlane((int)(threadIdx.x >> 6)) << 4;
    const int p    = blockIdx.x * 64 + lane;

    const float Ybout = Y_bout[0];
    const float qbout = q_bout[0];

    float y = y0p[0];
    float t = 0.0f;
    float Yv, dYv;
    float lossacc = 0.0f;

    // Y0, dY0 at (t=0, y0)
    ynet_eval(0.0f, y, Y_Win, Y_bin, Y_Whid, Y_bhid, Y_Wout, Ybout,
              sA, sB, sdA, sdB, lane, ub, Yv, dYv);

    for (int n = 0; n < NSTEP; ++n) {
        // ---- q = q_net(t, y) ----
        in_layer_fwd(t, y, q_Win, q_bin, sA, lane, ub);
        __syncthreads();
        hidden_fwd(q_Whid,        q_bhid,       sA, sB, lane, ub); __syncthreads();
        hidden_fwd(q_Whid + 4096, q_bhid + 64,  sB, sA, lane, ub); __syncthreads();
        hidden_fwd(q_Whid + 8192, q_bhid + 128, sA, sB, lane, ub); __syncthreads();
        float q = out_layer(sB, q_Wout, qbout, lane);

        // ---- SDE step + Euler residual target ----
        float dws  = dW[n * NPATH + p] * SQRT_DT;
        float y1   = fmaf(q, DT_F, y) + SIGMA_F * dws;
        float Ytil = fmaf(-q * q, DT_F, Yv) + (SIGMA_F * dYv) * dws;
        t += DT_F;

        // ---- (Y1, dY1) at (t+dt, y1) ----
        ynet_eval(t, y1, Y_Win, Y_bin, Y_Whid, Y_bhid, Y_Wout, Ybout,
                  sA, sB, sdA, sdB, lane, ub, Yv, dYv);

        float r = Yv - Ytil;
        lossacc = fmaf(r, r, lossacc);
        y = y1;
    }

    // terminal: g(y)=y^2, g'(y)=2y
    float r1 = Yv - y * y;
    float r2 = dYv - 2.0f * y;
    lossacc = fmaf(r1, r1, fmaf(r2, r2, lossacc));

    // one wave reduces (all waves hold identical per-path state)
    if (threadIdx.x < 64) {
        float v = lossacc;
#pragma unroll
        for (int off = 32; off > 0; off >>= 1) v += __shfl_down(v, off, 64);
        if (lane == 0) atomicAdd(out, v * (1.0f / (float)NPATH));
    }
}

// ---------- host launch ----------

extern "C" void kernel_launch(void* const* d_in, const int* in_sizes, int n_in,
                              void* d_out, int out_size, void* d_ws, size_t ws_size,
                              hipStream_t stream)
{
    const float* Y_Win  = (const float*)d_in[0];
    const float* Y_bin  = (const float*)d_in[1];
    const float* Y_Whid = (const float*)d_in[2];
    const float* Y_bhid = (const float*)d_in[3];
    const float* Y_Wout = (const float*)d_in[4];
    const float* Y_bout = (const float*)d_in[5];
    const float* q_Win  = (const float*)d_in[6];
    const float* q_bin  = (const float*)d_in[7];
    const float* q_Whid = (const float*)d_in[8];
    const float* q_bhid = (const float*)d_in[9];
    const float* q_Wout = (const float*)d_in[10];
    const float* q_bout = (const float*)d_in[11];
    const float* y0p    = (const float*)d_in[12];
    const float* dW     = (const float*)d_in[13];

    hipMemsetAsync(d_out, 0, sizeof(float), stream);
    fbsnn_kernel<<<dim3(NPATH / 64), dim3(256), 0, stream>>>(
        Y_Win, Y_bin, Y_Whid, Y_bhid, Y_Wout, Y_bout,
        q_Win, q_bin, q_Whid, q_bhid, q_Wout, q_bout,
        y0p, dW, (float*)d_out);
}

// Round 2
// 408.563 us; speedup vs baseline: 4.3185x; 4.3185x over previous
//
#include <hip/hip_runtime.h>

// FBSNN loss, phase-split fp32.
// Phase 1: sequential q-net scan, lane=hidden-unit, weights VGPR-resident,
//          h[k] broadcast via v_readlane. 512 blocks x 256 thr, 2 paths/wave.
// Phase 2: Y-net + forward tangent at all 51*4096 points, round-0 block
//          structure (lane=point, wave=16-unit slice, scalar weights).
// Phase 3: residual assembly + reduction.

#define NPATH   4096
#define NSTEP   50
#define DT_F    0.02f
#define SQRT_DT 0.14142136f
#define SIGMA_F 0.5f

__device__ __forceinline__ float bcast(float v, int l) {
    return __int_as_float(__builtin_amdgcn_readlane(__float_as_int(v), l));
}

// ================= Phase 1: q-net scan =================

__device__ __forceinline__ void hid_pair(const float (&wl)[64], float bh,
                                         float& hA, float& hB)
{
    float aA = bh, aB = bh;
#pragma unroll
    for (int k = 0; k < 64; ++k) {
        float w = wl[k];
        aA = fmaf(bcast(hA, k), w, aA);
        aB = fmaf(bcast(hB, k), w, aB);
    }
    hA = __sinf(aA);
    hB = __sinf(aB);
}

extern "C" __global__ void __launch_bounds__(256, 2)
fbsnn_phase1(const float* __restrict__ q_Win, const float* __restrict__ q_bin,
             const float* __restrict__ q_Whid, const float* __restrict__ q_bhid,
             const float* __restrict__ q_Wout, const float* __restrict__ q_bout,
             const float* __restrict__ y0p, const float* __restrict__ dW,
             float* __restrict__ y_ws, float* __restrict__ q_ws)
{
    const int lane = (int)(threadIdx.x & 63);
    const int w    = blockIdx.x * 4 + (int)(threadIdx.x >> 6);   // wave id 0..2047
    const int p0   = w * 2;
    const int p1   = p0 + 1;

    // lane u holds column u of each hidden weight matrix
    float W0[64], W1[64], W2[64];
#pragma unroll
    for (int k = 0; k < 64; ++k) {
        W0[k] = q_Whid[        k * 64 + lane];
        W1[k] = q_Whid[4096 +  k * 64 + lane];
        W2[k] = q_Whid[8192 +  k * 64 + lane];
    }
    const float win0 = q_Win[lane], win1 = q_Win[64 + lane], bi = q_bin[lane];
    const float b0 = q_bhid[lane], b1 = q_bhid[64 + lane], b2 = q_bhid[128 + lane];
    const float wo = q_Wout[lane];
    const float qb = q_bout[0];

    // dW preload, lane n holds step-n increment for this wave's two paths
    float vdwA = (lane < NSTEP) ? dW[lane * NPATH + p0] : 0.0f;
    float vdwB = (lane < NSTEP) ? dW[lane * NPATH + p1] : 0.0f;

    float yA = y0p[0];
    float yB = yA;

    for (int n = 0; n < NSTEP; ++n) {
        const float t = n * DT_F;
        if (lane == 0) {
            y_ws[n * NPATH + p0] = yA;
            y_ws[n * NPATH + p1] = yB;
        }
        float hA = __sinf(fmaf(t, win0, fmaf(yA, win1, bi)));
        float hB = __sinf(fmaf(t, win0, fmaf(yB, win1, bi)));
        hid_pair(W0, b0, hA, hB);
        hid_pair(W1, b1, hA, hB);
        hid_pair(W2, b2, hA, hB);
        float vA = hA * wo, vB = hB * wo;
#pragma unroll
        for (int off = 32; off > 0; off >>= 1) {
            vA += __shfl_xor(vA, off, 64);
            vB += __shfl_xor(vB, off, 64);
        }
        const float qA = vA + qb, qB = vB + qb;
        if (lane == 0) {
            q_ws[n * NPATH + p0] = qA;
            q_ws[n * NPATH + p1] = qB;
        }
        const float dwsA = bcast(vdwA, n) * SQRT_DT;
        const float dwsB = bcast(vdwB, n) * SQRT_DT;
        yA = fmaf(qA, DT_F, yA) + SIGMA_F * dwsA;
        yB = fmaf(qB, DT_F, yB) + SIGMA_F * dwsB;
    }
    if (lane == 0) {
        y_ws[NSTEP * NPATH + p0] = yA;
        y_ws[NSTEP * NPATH + p1] = yB;
    }
}

// ================= Phase 2: Y-net + tangent (round-0 structure) =================

__device__ __forceinline__ void in_layer_tan(float t, float y,
    const float* __restrict__ Win, const float* __restrict__ bin,
    float* __restrict__ dst, float* __restrict__ ddst, int lane, int ub)
{
#pragma unroll
    for (int i = 0; i < 16; ++i) {
        int u = ub + i;
        float w1 = Win[64 + u];
        float uv = fmaf(t, Win[u], fmaf(y, w1, bin[u]));
        float s, c;
        __sincosf(uv, &s, &c);
        dst[u * 64 + lane]  = s;
        ddst[u * 64 + lane] = c * w1;
    }
}

__device__ __forceinline__ void hidden_fwd_tan(
    const float* __restrict__ W, const float* __restrict__ b,
    const float* __restrict__ src, const float* __restrict__ dsrc,
    float* __restrict__ dst, float* __restrict__ ddst, int lane, int ub)
{
    float acc[16], dacc[16];
#pragma unroll
    for (int i = 0; i < 16; ++i) { acc[i] = b[ub + i]; dacc[i] = 0.0f; }
#pragma unroll 2
    for (int k = 0; k < 64; ++k) {
        float hk = src[k * 64 + lane];
        float dk = dsrc[k * 64 + lane];
        const float* wr = W + k * 64 + ub;
#pragma unroll
        for (int i = 0; i < 16; ++i) {
            float wv = wr[i];
            acc[i]  = fmaf(hk, wv, acc[i]);
            dacc[i] = fmaf(dk, wv, dacc[i]);
        }
    }
#pragma unroll
    for (int i = 0; i < 16; ++i) {
        float s, c;
        __sincosf(acc[i], &s, &c);
        dst[(ub + i) * 64 + lane]  = s;
        ddst[(ub + i) * 64 + lane] = c * dacc[i];
    }
}

__device__ __forceinline__ float out_layer(const float* __restrict__ src,
    const float* __restrict__ W, float bias, int lane)
{
    float acc = bias;
#pragma unroll 4
    for (int k = 0; k < 64; ++k) acc = fmaf(src[k * 64 + lane], W[k], acc);
    return acc;
}

extern "C" __global__ void __launch_bounds__(256)
fbsnn_phase2(const float* __restrict__ Y_Win, const float* __restrict__ Y_bin,
             const float* __restrict__ Y_Whid, const float* __restrict__ Y_bhid,
             const float* __restrict__ Y_Wout, const float* __restrict__ Y_bout,
             const float* __restrict__ y_ws, float* __restrict__ Y_ws,
             float* __restrict__ dY_ws)
{
    __shared__ float sA[4096];
    __shared__ float sB[4096];
    __shared__ float sdA[4096];
    __shared__ float sdB[4096];

    const int lane = (int)(threadIdx.x & 63);
    const int ub   = __builtin_amdgcn_readfirstlane((int)(threadIdx.x >> 6)) << 4;
    const int n    = (int)(blockIdx.x >> 6);            // 0..50
    const int p    = (int)((blockIdx.x & 63) << 6) | lane;

    const float t = n * DT_F;
    const float y = y_ws[n * NPATH + p];
    const float Ybout = Y_bout[0];

    in_layer_tan(t, y, Y_Win, Y_bin, sA, sdA, lane, ub);
    __syncthreads();
    hidden_fwd_tan(Y_Whid,        Y_bhid,       sA, sdA, sB, sdB, lane, ub); __syncthreads();
    hidden_fwd_tan(Y_Whid + 4096, Y_bhid + 64,  sB, sdB, sA, sdA, lane, ub); __syncthreads();
    hidden_fwd_tan(Y_Whid + 8192, Y_bhid + 128, sA, sdA, sB, sdB, lane, ub); __syncthreads();

    const float Yv  = out_layer(sB,  Y_Wout, Ybout, lane);
    const float dYv = out_layer(sdB, Y_Wout, 0.0f,  lane);

    if (threadIdx.x < 64) {
        Y_ws[n * NPATH + p]  = Yv;
        dY_ws[n * NPATH + p] = dYv;
    }
}

// ================= Phase 3: residuals + reduction =================

extern "C" __global__ void __launch_bounds__(256)
fbsnn_phase3(const float* __restrict__ y_ws, const float* __restrict__ q_ws,
             const float* __restrict__ Y_ws, const float* __restrict__ dY_ws,
             const float* __restrict__ dW, float* __restrict__ out)
{
    const int p = blockIdx.x * 256 + threadIdx.x;

    float Yc  = Y_ws[p];                 // n = 0
    float acc = 0.0f;
#pragma unroll 5
    for (int n = 0; n < NSTEP; ++n) {
        float q    = q_ws[n * NPATH + p];
        float dYc  = dY_ws[n * NPATH + p];
        float dws  = dW[n * NPATH + p] * SQRT_DT;
        float Yn   = Y_ws[(n + 1) * NPATH + p];
        float Ytil = fmaf(-q * q, DT_F, Yc) + (SIGMA_F * dYc) * dws;
        float r    = Yn - Ytil;
        acc = fmaf(r, r, acc);
        Yc = Yn;
    }
    float y50  = y_ws[NSTEP * NPATH + p];
    float dY50 = dY_ws[NSTEP * NPATH + p];
    float r1 = Yc - y50 * y50;
    float r2 = dY50 - 2.0f * y50;
    acc = fmaf(r1, r1, fmaf(r2, r2, acc));

    float v = acc;
#pragma unroll
    for (int off = 32; off > 0; off >>= 1) v += __shfl_down(v, off, 64);
    if ((threadIdx.x & 63) == 0) atomicAdd(out, v * (1.0f / (float)NPATH));
}

// ================= host launch =================

extern "C" void kernel_launch(void* const* d_in, const int* in_sizes, int n_in,
                              void* d_out, int out_size, void* d_ws, size_t ws_size,
                              hipStream_t stream)
{
    const float* Y_Win  = (const float*)d_in[0];
    const float* Y_bin  = (const float*)d_in[1];
    const float* Y_Whid = (const float*)d_in[2];
    const float* Y_bhid = (const float*)d_in[3];
    const float* Y_Wout = (const float*)d_in[4];
    const float* Y_bout = (const float*)d_in[5];
    const float* q_Win  = (const float*)d_in[6];
    const float* q_bin  = (const float*)d_in[7];
    const float* q_Whid = (const float*)d_in[8];
    const float* q_bhid = (const float*)d_in[9];
    const float* q_Wout = (const float*)d_in[10];
    const float* q_bout = (const float*)d_in[11];
    const float* y0p    = (const float*)d_in[12];
    const float* dW     = (const float*)d_in[13];

    float* ws    = (float*)d_ws;
    float* y_ws  = ws;                          // 51*4096
    float* q_ws  = ws + 51 * NPATH;             // 50*4096
    float* Y_ws  = ws + 101 * NPATH;            // 51*4096
    float* dY_ws = ws + 152 * NPATH;            // 51*4096

    hipMemsetAsync(d_out, 0, sizeof(float), stream);

    fbsnn_phase1<<<dim3(512), dim3(256), 0, stream>>>(
        q_Win, q_bin, q_Whid, q_bhid, q_Wout, q_bout, y0p, dW, y_ws, q_ws);

    fbsnn_phase2<<<dim3(51 * 64), dim3(256), 0, stream>>>(
        Y_Win, Y_bin, Y_Whid, Y_bhid, Y_Wout, Y_bout, y_ws, Y_ws, dY_ws);

    fbsnn_phase3<<<dim3(NPATH / 256), dim3(256), 0, stream>>>(
        y_ws, q_ws, Y_ws, dY_ws, dW, (float*)d_out);
}

// Round 3
// 281.029 us; speedup vs baseline: 6.2783x; 1.4538x over previous
//
#include <hip/hip_runtime.h>

// FBSNN loss.
// Phase 1: sequential q-net scan, lane=hidden-unit, weights VGPR-resident (fp32).
// Phase 2: Y-net + forward tangent at all 51*4096 points via bf16 MFMA,
//          "points-as-N" orientation: C[u][p], lane keeps fixed point p=lane&31,
//          layer transitions via half-wave shfl_xor(32) exchange. No barriers in
//          the tile loop; weight A-frags prebuilt in a 36KB LDS table per block.
// Phase 3: residual assembly + reduction (fp32).

#define NPATH   4096
#define NSTEP   50
#define DT_F    0.02f
#define SQRT_DT 0.14142136f
#define SIGMA_F 0.5f

typedef __attribute__((ext_vector_type(8)))  short s16x8;
typedef __attribute__((ext_vector_type(16))) float f32x16;

__device__ __forceinline__ float bcast(float v, int l) {
    return __int_as_float(__builtin_amdgcn_readlane(__float_as_int(v), l));
}

// pack two f32 -> two bf16 (RNE) in one u32 (low = a, high = b)
__device__ __forceinline__ unsigned pkbf(float a, float b) {
    unsigned ua = __float_as_uint(a), ub = __float_as_uint(b);
    ua += 0x7fffu + ((ua >> 16) & 1u);
    ub += 0x7fffu + ((ub >> 16) & 1u);
    return (ua >> 16) | (ub & 0xffff0000u);
}

__device__ __forceinline__ s16x8 frag4(unsigned a, unsigned b, unsigned c, unsigned d) {
    union { unsigned u[4]; s16x8 s; } x;
    x.u[0] = a; x.u[1] = b; x.u[2] = c; x.u[3] = d;
    return x.s;
}

__device__ __forceinline__ s16x8 frag_of(uint4 v) {
    union { uint4 q; s16x8 s; } x; x.q = v; return x.s;
}

__device__ __forceinline__ f32x16 zf() {
    f32x16 v;
#pragma unroll
    for (int i = 0; i < 16; ++i) v[i] = 0.0f;
    return v;
}

__device__ __forceinline__ unsigned sx32(unsigned v) {
    return (unsigned)__shfl_xor((int)v, 32, 64);
}

// ================= Phase 1: q-net scan (unchanged from round 2) =================

__device__ __forceinline__ void hid_pair(const float (&wl)[64], float bh,
                                         float& hA, float& hB)
{
    float aA = bh, aB = bh;
#pragma unroll
    for (int k = 0; k < 64; ++k) {
        float w = wl[k];
        aA = fmaf(bcast(hA, k), w, aA);
        aB = fmaf(bcast(hB, k), w, aB);
    }
    hA = __sinf(aA);
    hB = __sinf(aB);
}

extern "C" __global__ void __launch_bounds__(256, 2)
fbsnn_phase1(const float* __restrict__ q_Win, const float* __restrict__ q_bin,
             const float* __restrict__ q_Whid, const float* __restrict__ q_bhid,
             const float* __restrict__ q_Wout, const float* __restrict__ q_bout,
             const float* __restrict__ y0p, const float* __restrict__ dW,
             float* __restrict__ y_ws, float* __restrict__ q_ws)
{
    const int lane = (int)(threadIdx.x & 63);
    const int w    = blockIdx.x * 4 + (int)(threadIdx.x >> 6);
    const int p0   = w * 2;
    const int p1   = p0 + 1;

    float W0[64], W1[64], W2[64];
#pragma unroll
    for (int k = 0; k < 64; ++k) {
        W0[k] = q_Whid[        k * 64 + lane];
        W1[k] = q_Whid[4096 +  k * 64 + lane];
        W2[k] = q_Whid[8192 +  k * 64 + lane];
    }
    const float win0 = q_Win[lane], win1 = q_Win[64 + lane], bi = q_bin[lane];
    const float b0 = q_bhid[lane], b1 = q_bhid[64 + lane], b2 = q_bhid[128 + lane];
    const float wo = q_Wout[lane];
    const float qb = q_bout[0];

    float vdwA = (lane < NSTEP) ? dW[lane * NPATH + p0] : 0.0f;
    float vdwB = (lane < NSTEP) ? dW[lane * NPATH + p1] : 0.0f;

    float yA = y0p[0];
    float yB = yA;

    for (int n = 0; n < NSTEP; ++n) {
        const float t = n * DT_F;
        if (lane == 0) {
            y_ws[n * NPATH + p0] = yA;
            y_ws[n * NPATH + p1] = yB;
        }
        float hA = __sinf(fmaf(t, win0, fmaf(yA, win1, bi)));
        float hB = __sinf(fmaf(t, win0, fmaf(yB, win1, bi)));
        hid_pair(W0, b0, hA, hB);
        hid_pair(W1, b1, hA, hB);
        hid_pair(W2, b2, hA, hB);
        float vA = hA * wo, vB = hB * wo;
#pragma unroll
        for (int off = 32; off > 0; off >>= 1) {
            vA += __shfl_xor(vA, off, 64);
            vB += __shfl_xor(vB, off, 64);
        }
        const float qA = vA + qb, qB = vB + qb;
        if (lane == 0) {
            q_ws[n * NPATH + p0] = qA;
            q_ws[n * NPATH + p1] = qB;
        }
        const float dwsA = bcast(vdwA, n) * SQRT_DT;
        const float dwsB = bcast(vdwB, n) * SQRT_DT;
        yA = fmaf(qA, DT_F, yA) + SIGMA_F * dwsA;
        yB = fmaf(qB, DT_F, yB) + SIGMA_F * dwsB;
    }
    if (lane == 0) {
        y_ws[NSTEP * NPATH + p0] = yA;
        y_ws[NSTEP * NPATH + p1] = yB;
    }
}

// ================= Phase 2: Y-net + tangent via MFMA =================
//
// C[u][p] = sum_k W[k][u] * h[k][p] via mfma_f32_32x32x16_bf16:
//   A[m=u][k] = W[k][u], B[k][n=p] = h[k][p].
// Lane l: m/n index = l&31, h-half = l>>5.
// A-frag elem i <-> k = 16b + 8h + i. C/D: col = l&31, row = (reg&3)+8*(reg>>2)+4h.
//
// Layer transition: lane holds rows with bit2==h, needs k's with bit3==h;
// missing half comes from partner lane l^32 (one shfl_xor per 2 packed words).

#define NTILES 1632          // 208896 points / 128 per block
#define P2GRID 512

// transition: C (pre-act f32) + Ctan (tangent pre-act) -> next-layer B-frags
__device__ __forceinline__ void transition(
    const f32x16& Cf0, const f32x16& Cf1, const f32x16& Ct0, const f32x16& Ct1,
    int h, s16x8* Bf, s16x8* Bt)
{
    unsigned fw[16], tw[16];
#pragma unroll
    for (int tau = 0; tau < 2; ++tau) {
        const f32x16& P = tau ? Cf1 : Cf0;
        const f32x16& D = tau ? Ct1 : Ct0;
#pragma unroll
        for (int j = 0; j < 8; ++j) {
            float s0, c0, s1, c1;
            __sincosf(P[2 * j],     &s0, &c0);
            __sincosf(P[2 * j + 1], &s1, &c1);
            fw[tau * 8 + j] = pkbf(s0, s1);
            tw[tau * 8 + j] = pkbf(c0 * D[2 * j], c1 * D[2 * j + 1]);
        }
    }
#pragma unroll
    for (int b = 0; b < 4; ++b) {
        const int q = (b >> 1) * 8 + (b & 1) * 4;
        unsigned fs0 = h ? fw[q + 2] : fw[q + 0];
        unsigned fs1 = h ? fw[q + 3] : fw[q + 1];
        unsigned fx0 = h ? fw[q + 0] : fw[q + 2];
        unsigned fx1 = h ? fw[q + 1] : fw[q + 3];
        unsigned ts0 = h ? tw[q + 2] : tw[q + 0];
        unsigned ts1 = h ? tw[q + 3] : tw[q + 1];
        unsigned tx0 = h ? tw[q + 0] : tw[q + 2];
        unsigned tx1 = h ? tw[q + 1] : tw[q + 3];
        unsigned fr0 = sx32(fx0), fr1 = sx32(fx1);
        unsigned tr0 = sx32(tx0), tr1 = sx32(tx1);
        Bf[b] = h ? frag4(fr0, fr1, fs0, fs1) : frag4(fs0, fs1, fr0, fr1);
        Bt[b] = h ? frag4(tr0, tr1, ts0, ts1) : frag4(ts0, ts1, tr0, tr1);
    }
}

extern "C" __global__ void __launch_bounds__(256, 2)
fbsnn_phase2(const float* __restrict__ Y_Win, const float* __restrict__ Y_bin,
             const float* __restrict__ Y_Whid, const float* __restrict__ Y_bhid,
             const float* __restrict__ Y_Wout, const float* __restrict__ Y_bout,
             const float* __restrict__ y_ws, float* __restrict__ Y_ws,
             float* __restrict__ dY_ws)
{
    // frag table: e=0..1 Win(tau); e=2..31 hidden (2 + L*10 + tau*5 + b, b=4 is bias);
    // e=32..35 Wout. 36 entries x 64 lanes x 16B = 36 KB.
    __shared__ uint4 fragLDS[36 * 64];

    const int tid = (int)threadIdx.x;
    const int wv  = tid >> 6;
    const int l   = tid & 63;
    const int h   = l >> 5;
    const int m   = l & 31;

    // ---- build per-lane A-fragments (split across 4 waves) ----
    for (int e = wv; e < 36; e += 4) {
        unsigned w0 = 0, w1 = 0, w2 = 0, w3 = 0;
        if (e < 2) {                       // input layer: A[u][k]: k0=t, k1=y, k2=bias
            int u = 32 * e + m;
            if (h == 0) {
                w0 = pkbf(Y_Win[u], Y_Win[64 + u]);
                w1 = pkbf(Y_bin[u], 0.0f);
            }
        } else if (e < 32) {
            int e2 = e - 2;
            int L = e2 / 10, rem = e2 % 10;
            int tau = rem / 5, b = rem % 5;
            int u = 32 * tau + m;
            if (b < 4) {
                int k0 = 16 * b + 8 * h;
                w0 = pkbf(Y_Whid[L * 4096 + (k0 + 0) * 64 + u], Y_Whid[L * 4096 + (k0 + 1) * 64 + u]);
                w1 = pkbf(Y_Whid[L * 4096 + (k0 + 2) * 64 + u], Y_Whid[L * 4096 + (k0 + 3) * 64 + u]);
                w2 = pkbf(Y_Whid[L * 4096 + (k0 + 4) * 64 + u], Y_Whid[L * 4096 + (k0 + 5) * 64 + u]);
                w3 = pkbf(Y_Whid[L * 4096 + (k0 + 6) * 64 + u], Y_Whid[L * 4096 + (k0 + 7) * 64 + u]);
            } else {                        // bias as k-row 64 (+8h offset handled by h==0,i==0)
                if (h == 0) w0 = pkbf(Y_bhid[L * 64 + u], 0.0f);
            }
        } else {                            // output layer: A[0][k] = Wout[k]
            int b = e - 32;
            if (m == 0) {
                int k0 = 16 * b + 8 * h;
                w0 = pkbf(Y_Wout[k0 + 0], Y_Wout[k0 + 1]);
                w1 = pkbf(Y_Wout[k0 + 2], Y_Wout[k0 + 3]);
                w2 = pkbf(Y_Wout[k0 + 4], Y_Wout[k0 + 5]);
                w3 = pkbf(Y_Wout[k0 + 6], Y_Wout[k0 + 7]);
            }
        }
        fragLDS[e * 64 + l] = make_uint4(w0, w1, w2, w3);
    }
    __syncthreads();

    const float bout = Y_bout[0];
    const s16x8 Btn  = frag4(h ? 0u : pkbf(0.0f, 1.0f), 0u, 0u, 0u);  // tangent seed dy=1
    const s16x8 Bone = frag4(h ? 0u : pkbf(1.0f, 0.0f), 0u, 0u, 0u);  // bias "ones" row

    for (int tile = (int)blockIdx.x; tile < NTILES; tile += P2GRID) {
        const int point = tile * 128 + wv * 32 + m;
        const int n = point >> 12;
        const float t = n * DT_F;
        const float y = y_ws[point];

        const s16x8 Bty = frag4(h ? 0u : pkbf(t, y), h ? 0u : pkbf(1.0f, 0.0f), 0u, 0u);

        // ---- input layer (K=2 + bias row, one k-block) ----
        f32x16 Cf0 = zf(), Cf1 = zf(), Ct0 = zf(), Ct1 = zf();
        {
            s16x8 A0 = frag_of(fragLDS[0 * 64 + l]);
            s16x8 A1 = frag_of(fragLDS[1 * 64 + l]);
            Cf0 = __builtin_amdgcn_mfma_f32_32x32x16_bf16(A0, Bty, Cf0, 0, 0, 0);
            Cf1 = __builtin_amdgcn_mfma_f32_32x32x16_bf16(A1, Bty, Cf1, 0, 0, 0);
            Ct0 = __builtin_amdgcn_mfma_f32_32x32x16_bf16(A0, Btn, Ct0, 0, 0, 0);
            Ct1 = __builtin_amdgcn_mfma_f32_32x32x16_bf16(A1, Btn, Ct1, 0, 0, 0);
        }
        s16x8 Bf[4], Bt[4];
        transition(Cf0, Cf1, Ct0, Ct1, h, Bf, Bt);

        // ---- 3 hidden layers ----
#pragma unroll
        for (int L = 0; L < 3; ++L) {
            Cf0 = zf(); Cf1 = zf(); Ct0 = zf(); Ct1 = zf();
#pragma unroll
            for (int b = 0; b < 4; ++b) {
                s16x8 A0 = frag_of(fragLDS[(2 + L * 10 + 0 + b) * 64 + l]);
                s16x8 A1 = frag_of(fragLDS[(2 + L * 10 + 5 + b) * 64 + l]);
                Cf0 = __builtin_amdgcn_mfma_f32_32x32x16_bf16(A0, Bf[b], Cf0, 0, 0, 0);
                Ct0 = __builtin_amdgcn_mfma_f32_32x32x16_bf16(A0, Bt[b], Ct0, 0, 0, 0);
                Cf1 = __builtin_amdgcn_mfma_f32_32x32x16_bf16(A1, Bf[b], Cf1, 0, 0, 0);
                Ct1 = __builtin_amdgcn_mfma_f32_32x32x16_bf16(A1, Bt[b], Ct1, 0, 0, 0);
            }
            {   // bias (fwd only; tangent bias = 0)
                s16x8 Ab0 = frag_of(fragLDS[(2 + L * 10 + 0 + 4) * 64 + l]);
                s16x8 Ab1 = frag_of(fragLDS[(2 + L * 10 + 5 + 4) * 64 + l]);
                Cf0 = __builtin_amdgcn_mfma_f32_32x32x16_bf16(Ab0, Bone, Cf0, 0, 0, 0);
                Cf1 = __builtin_amdgcn_mfma_f32_32x32x16_bf16(Ab1, Bone, Cf1, 0, 0, 0);
            }
            transition(Cf0, Cf1, Ct0, Ct1, h, Bf, Bt);
        }

        // ---- output layer: row 0 = Wout . h ----
        f32x16 Cof = zf(), Cot = zf();
#pragma unroll
        for (int b = 0; b < 4; ++b) {
            s16x8 Ao = frag_of(fragLDS[(32 + b) * 64 + l]);
            Cof = __builtin_amdgcn_mfma_f32_32x32x16_bf16(Ao, Bf[b], Cof, 0, 0, 0);
            Cot = __builtin_amdgcn_mfma_f32_32x32x16_bf16(Ao, Bt[b], Cot, 0, 0, 0);
        }
        if (h == 0) {       // row 0 lives at reg 0 of the h==0 half; col = m = point
            Y_ws[point]  = Cof[0] + bout;
            dY_ws[point] = Cot[0];
        }
    }
}

// ================= Phase 3: residuals + reduction =================

extern "C" __global__ void __launch_bounds__(256)
fbsnn_phase3(const float* __restrict__ y_ws, const float* __restrict__ q_ws,
             const float* __restrict__ Y_ws, const float* __restrict__ dY_ws,
             const float* __restrict__ dW, float* __restrict__ out)
{
    const int p = blockIdx.x * 256 + threadIdx.x;

    float Yc  = Y_ws[p];
    float acc = 0.0f;
#pragma unroll 5
    for (int n = 0; n < NSTEP; ++n) {
        float q    = q_ws[n * NPATH + p];
        float dYc  = dY_ws[n * NPATH + p];
        float dws  = dW[n * NPATH + p] * SQRT_DT;
        float Yn   = Y_ws[(n + 1) * NPATH + p];
        float Ytil = fmaf(-q * q, DT_F, Yc) + (SIGMA_F * dYc) * dws;
        float r    = Yn - Ytil;
        acc = fmaf(r, r, acc);
        Yc = Yn;
    }
    float y50  = y_ws[NSTEP * NPATH + p];
    float dY50 = dY_ws[NSTEP * NPATH + p];
    float r1 = Yc - y50 * y50;
    float r2 = dY50 - 2.0f * y50;
    acc = fmaf(r1, r1, fmaf(r2, r2, acc));

    float v = acc;
#pragma unroll
    for (int off = 32; off > 0; off >>= 1) v += __shfl_down(v, off, 64);
    if ((threadIdx.x & 63) == 0) atomicAdd(out, v * (1.0f / (float)NPATH));
}

// ================= host launch =================

extern "C" void kernel_launch(void* const* d_in, const int* in_sizes, int n_in,
                              void* d_out, int out_size, void* d_ws, size_t ws_size,
                              hipStream_t stream)
{
    const float* Y_Win  = (const float*)d_in[0];
    const float* Y_bin  = (const float*)d_in[1];
    const float* Y_Whid = (const float*)d_in[2];
    const float* Y_bhid = (const float*)d_in[3];
    const float* Y_Wout = (const float*)d_in[4];
    const float* Y_bout = (const float*)d_in[5];
    const float* q_Win  = (const float*)d_in[6];
    const float* q_bin  = (const float*)d_in[7];
    const float* q_Whid = (const float*)d_in[8];
    const float* q_bhid = (const float*)d_in[9];
    const float* q_Wout = (const float*)d_in[10];
    const float* q_bout = (const float*)d_in[11];
    const float* y0p    = (const float*)d_in[12];
    const float* dW     = (const float*)d_in[13];

    float* ws    = (float*)d_ws;
    float* y_ws  = ws;                          // 51*4096
    float* q_ws  = ws + 51 * NPATH;             // 50*4096
    float* Y_ws  = ws + 101 * NPATH;            // 51*4096
    float* dY_ws = ws + 152 * NPATH;            // 51*4096

    hipMemsetAsync(d_out, 0, sizeof(float), stream);

    fbsnn_phase1<<<dim3(512), dim3(256), 0, stream>>>(
        q_Win, q_bin, q_Whid, q_bhid, q_Wout, q_bout, y0p, dW, y_ws, q_ws);

    fbsnn_phase2<<<dim3(P2GRID), dim3(256), 0, stream>>>(
        Y_Win, Y_bin, Y_Whid, Y_bhid, Y_Wout, Y_bout, y_ws, Y_ws, dY_ws);

    fbsnn_phase3<<<dim3(NPATH / 256), dim3(256), 0, stream>>>(
        y_ws, q_ws, Y_ws, dY_ws, dW, (float*)d_out);
}

// Round 4
// 259.286 us; speedup vs baseline: 6.8047x; 1.0839x over previous
//
#include <hip/hip_runtime.h>

// FBSNN loss.
// Phase 1: sequential q-net scan via bf16 MFMA, fwd-only. 128 blocks x 64 thr,
//          1 wave = 32 paths x 50 steps. Weight A-frags REGISTER-resident
//          (~240 VGPR, launch_bounds(64,1)); no LDS, no barriers in the loop.
// Phase 2: Y-net + forward tangent at all 51*4096 points via bf16 MFMA,
//          "points-as-N": C[u][p], lane keeps fixed point p=lane&31, layer
//          transitions via half-wave shfl_xor(32). 36KB LDS frag table.
// Phase 3: residual assembly + reduction (fp32).

#define NPATH   4096
#define NSTEP   50
#define DT_F    0.02f
#define SQRT_DT 0.14142136f
#define SIGMA_F 0.5f

typedef __attribute__((ext_vector_type(8)))  short s16x8;
typedef __attribute__((ext_vector_type(16))) float f32x16;

// pack two f32 -> two bf16 (RNE) in one u32 (low = a, high = b)
__device__ __forceinline__ unsigned pkbf(float a, float b) {
    unsigned ua = __float_as_uint(a), ub = __float_as_uint(b);
    ua += 0x7fffu + ((ua >> 16) & 1u);
    ub += 0x7fffu + ((ub >> 16) & 1u);
    return (ua >> 16) | (ub & 0xffff0000u);
}

__device__ __forceinline__ s16x8 frag4(unsigned a, unsigned b, unsigned c, unsigned d) {
    union { unsigned u[4]; s16x8 s; } x;
    x.u[0] = a; x.u[1] = b; x.u[2] = c; x.u[3] = d;
    return x.s;
}

__device__ __forceinline__ s16x8 frag_of(uint4 v) {
    union { uint4 q; s16x8 s; } x; x.q = v; return x.s;
}

__device__ __forceinline__ f32x16 zf() {
    f32x16 v;
#pragma unroll
    for (int i = 0; i < 16; ++i) v[i] = 0.0f;
    return v;
}

__device__ __forceinline__ unsigned sx32(unsigned v) {
    return (unsigned)__shfl_xor((int)v, 32, 64);
}

// fwd+tangent transition (phase 2)
__device__ __forceinline__ void transition(
    const f32x16& Cf0, const f32x16& Cf1, const f32x16& Ct0, const f32x16& Ct1,
    int h, s16x8* Bf, s16x8* Bt)
{
    unsigned fw[16], tw[16];
#pragma unroll
    for (int tau = 0; tau < 2; ++tau) {
        const f32x16& P = tau ? Cf1 : Cf0;
        const f32x16& D = tau ? Ct1 : Ct0;
#pragma unroll
        for (int j = 0; j < 8; ++j) {
            float s0, c0, s1, c1;
            __sincosf(P[2 * j],     &s0, &c0);
            __sincosf(P[2 * j + 1], &s1, &c1);
            fw[tau * 8 + j] = pkbf(s0, s1);
            tw[tau * 8 + j] = pkbf(c0 * D[2 * j], c1 * D[2 * j + 1]);
        }
    }
#pragma unroll
    for (int b = 0; b < 4; ++b) {
        const int q = (b >> 1) * 8 + (b & 1) * 4;
        unsigned fs0 = h ? fw[q + 2] : fw[q + 0];
        unsigned fs1 = h ? fw[q + 3] : fw[q + 1];
        unsigned fx0 = h ? fw[q + 0] : fw[q + 2];
        unsigned fx1 = h ? fw[q + 1] : fw[q + 3];
        unsigned ts0 = h ? tw[q + 2] : tw[q + 0];
        unsigned ts1 = h ? tw[q + 3] : tw[q + 1];
        unsigned tx0 = h ? tw[q + 0] : tw[q + 2];
        unsigned tx1 = h ? tw[q + 1] : tw[q + 3];
        unsigned fr0 = sx32(fx0), fr1 = sx32(fx1);
        unsigned tr0 = sx32(tx0), tr1 = sx32(tx1);
        Bf[b] = h ? frag4(fr0, fr1, fs0, fs1) : frag4(fs0, fs1, fr0, fr1);
        Bt[b] = h ? frag4(tr0, tr1, ts0, ts1) : frag4(ts0, ts1, tr0, tr1);
    }
}

// fwd-only transition (phase 1)
__device__ __forceinline__ void transition_fwd(
    const f32x16& Cf0, const f32x16& Cf1, int h, s16x8* Bf)
{
    unsigned fw[16];
#pragma unroll
    for (int tau = 0; tau < 2; ++tau) {
        const f32x16& P = tau ? Cf1 : Cf0;
#pragma unroll
        for (int j = 0; j < 8; ++j)
            fw[tau * 8 + j] = pkbf(__sinf(P[2 * j]), __sinf(P[2 * j + 1]));
    }
#pragma unroll
    for (int b = 0; b < 4; ++b) {
        const int q = (b >> 1) * 8 + (b & 1) * 4;
        unsigned fs0 = h ? fw[q + 2] : fw[q + 0];
        unsigned fs1 = h ? fw[q + 3] : fw[q + 1];
        unsigned fx0 = h ? fw[q + 0] : fw[q + 2];
        unsigned fx1 = h ? fw[q + 1] : fw[q + 3];
        unsigned fr0 = sx32(fx0), fr1 = sx32(fx1);
        Bf[b] = h ? frag4(fr0, fr1, fs0, fs1) : frag4(fs0, fs1, fr0, fr1);
    }
}

// ================= Phase 1: q-net scan via MFMA, register-resident weights ====

extern "C" __global__ void __launch_bounds__(64, 1)
fbsnn_phase1(const float* __restrict__ q_Win, const float* __restrict__ q_bin,
             const float* __restrict__ q_Whid, const float* __restrict__ q_bhid,
             const float* __restrict__ q_Wout, const float* __restrict__ q_bout,
             const float* __restrict__ y0p, const float* __restrict__ dW,
             float* __restrict__ y_ws, float* __restrict__ q_ws)
{
    const int l = (int)(threadIdx.x & 63);
    const int h = l >> 5;
    const int m = l & 31;
    const int p = (int)blockIdx.x * 32 + m;

    // ---- build register-resident A-fragments ----
    s16x8 Ain[2], Ahid[3][2][5], Aout[4];
#pragma unroll
    for (int tau = 0; tau < 2; ++tau) {
        int u = 32 * tau + m;
        unsigned w0 = 0, w1 = 0;
        if (h == 0) { w0 = pkbf(q_Win[u], q_Win[64 + u]); w1 = pkbf(q_bin[u], 0.0f); }
        Ain[tau] = frag4(w0, w1, 0u, 0u);
    }
#pragma unroll
    for (int L = 0; L < 3; ++L) {
#pragma unroll
        for (int tau = 0; tau < 2; ++tau) {
            int u = 32 * tau + m;
            const float* Wp = q_Whid + L * 4096 + u;
#pragma unroll
            for (int b = 0; b < 4; ++b) {
                int k0 = 16 * b + 8 * h;
                Ahid[L][tau][b] = frag4(
                    pkbf(Wp[(k0 + 0) * 64], Wp[(k0 + 1) * 64]),
                    pkbf(Wp[(k0 + 2) * 64], Wp[(k0 + 3) * 64]),
                    pkbf(Wp[(k0 + 4) * 64], Wp[(k0 + 5) * 64]),
                    pkbf(Wp[(k0 + 6) * 64], Wp[(k0 + 7) * 64]));
            }
            unsigned bw = (h == 0) ? pkbf(q_bhid[L * 64 + u], 0.0f) : 0u;
            Ahid[L][tau][4] = frag4(bw, 0u, 0u, 0u);
        }
    }
#pragma unroll
    for (int b = 0; b < 4; ++b) {
        unsigned w0 = 0, w1 = 0, w2 = 0, w3 = 0;
        if (m == 0) {
            int k0 = 16 * b + 8 * h;
            w0 = pkbf(q_Wout[k0 + 0], q_Wout[k0 + 1]);
            w1 = pkbf(q_Wout[k0 + 2], q_Wout[k0 + 3]);
            w2 = pkbf(q_Wout[k0 + 4], q_Wout[k0 + 5]);
            w3 = pkbf(q_Wout[k0 + 6], q_Wout[k0 + 7]);
        }
        Aout[b] = frag4(w0, w1, w2, w3);
    }
    const float qb = q_bout[0];
    const s16x8 Bone = frag4(h ? 0u : pkbf(1.0f, 0.0f), 0u, 0u, 0u);

    float y = y0p[0];

    for (int n = 0; n < NSTEP; ++n) {
        const float t = n * DT_F;
        if (h == 0) y_ws[n * NPATH + p] = y;

        const s16x8 Bty = frag4(h ? 0u : pkbf(t, y), h ? 0u : pkbf(1.0f, 0.0f), 0u, 0u);

        f32x16 Cf0 = zf(), Cf1 = zf();
        Cf0 = __builtin_amdgcn_mfma_f32_32x32x16_bf16(Ain[0], Bty, Cf0, 0, 0, 0);
        Cf1 = __builtin_amdgcn_mfma_f32_32x32x16_bf16(Ain[1], Bty, Cf1, 0, 0, 0);
        s16x8 Bf[4];
        transition_fwd(Cf0, Cf1, h, Bf);

#pragma unroll
        for (int L = 0; L < 3; ++L) {
            Cf0 = zf(); Cf1 = zf();
#pragma unroll
            for (int b = 0; b < 4; ++b) {
                Cf0 = __builtin_amdgcn_mfma_f32_32x32x16_bf16(Ahid[L][0][b], Bf[b], Cf0, 0, 0, 0);
                Cf1 = __builtin_amdgcn_mfma_f32_32x32x16_bf16(Ahid[L][1][b], Bf[b], Cf1, 0, 0, 0);
            }
            Cf0 = __builtin_amdgcn_mfma_f32_32x32x16_bf16(Ahid[L][0][4], Bone, Cf0, 0, 0, 0);
            Cf1 = __builtin_amdgcn_mfma_f32_32x32x16_bf16(Ahid[L][1][4], Bone, Cf1, 0, 0, 0);
            transition_fwd(Cf0, Cf1, h, Bf);
        }

        f32x16 Cof = zf();
#pragma unroll
        for (int b = 0; b < 4; ++b)
            Cof = __builtin_amdgcn_mfma_f32_32x32x16_bf16(Aout[b], Bf[b], Cof, 0, 0, 0);

        const float q = Cof[0] + qb;                 // valid at h==0, col=m
        const float dwn = dW[n * NPATH + p];
        if (h == 0) q_ws[n * NPATH + p] = q;
        y = fmaf(q, DT_F, y) + SIGMA_F * (dwn * SQRT_DT);
    }
    if (h == 0) y_ws[NSTEP * NPATH + p] = y;
}

// ================= Phase 2: Y-net + tangent via MFMA (round-3 structure) ======

#define NTILES 1632          // 208896 points / 128 per block
#define P2GRID 512

extern "C" __global__ void __launch_bounds__(256, 2)
fbsnn_phase2(const float* __restrict__ Y_Win, const float* __restrict__ Y_bin,
             const float* __restrict__ Y_Whid, const float* __restrict__ Y_bhid,
             const float* __restrict__ Y_Wout, const float* __restrict__ Y_bout,
             const float* __restrict__ y_ws, float* __restrict__ Y_ws,
             float* __restrict__ dY_ws)
{
    __shared__ uint4 fragLDS[36 * 64];

    const int tid = (int)threadIdx.x;
    const int wv  = tid >> 6;
    const int l   = tid & 63;
    const int h   = l >> 5;
    const int m   = l & 31;

    for (int e = wv; e < 36; e += 4) {
        unsigned w0 = 0, w1 = 0, w2 = 0, w3 = 0;
        if (e < 2) {
            int u = 32 * e + m;
            if (h == 0) {
                w0 = pkbf(Y_Win[u], Y_Win[64 + u]);
                w1 = pkbf(Y_bin[u], 0.0f);
            }
        } else if (e < 32) {
            int e2 = e - 2;
            int L = e2 / 10, rem = e2 % 10;
            int tau = rem / 5, b = rem % 5;
            int u = 32 * tau + m;
            if (b < 4) {
                int k0 = 16 * b + 8 * h;
                w0 = pkbf(Y_Whid[L * 4096 + (k0 + 0) * 64 + u], Y_Whid[L * 4096 + (k0 + 1) * 64 + u]);
                w1 = pkbf(Y_Whid[L * 4096 + (k0 + 2) * 64 + u], Y_Whid[L * 4096 + (k0 + 3) * 64 + u]);
                w2 = pkbf(Y_Whid[L * 4096 + (k0 + 4) * 64 + u], Y_Whid[L * 4096 + (k0 + 5) * 64 + u]);
                w3 = pkbf(Y_Whid[L * 4096 + (k0 + 6) * 64 + u], Y_Whid[L * 4096 + (k0 + 7) * 64 + u]);
            } else {
                if (h == 0) w0 = pkbf(Y_bhid[L * 64 + u], 0.0f);
            }
        } else {
            int b = e - 32;
            if (m == 0) {
                int k0 = 16 * b + 8 * h;
                w0 = pkbf(Y_Wout[k0 + 0], Y_Wout[k0 + 1]);
                w1 = pkbf(Y_Wout[k0 + 2], Y_Wout[k0 + 3]);
                w2 = pkbf(Y_Wout[k0 + 4], Y_Wout[k0 + 5]);
                w3 = pkbf(Y_Wout[k0 + 6], Y_Wout[k0 + 7]);
            }
        }
        fragLDS[e * 64 + l] = make_uint4(w0, w1, w2, w3);
    }
    __syncthreads();

    const float bout = Y_bout[0];
    const s16x8 Btn  = frag4(h ? 0u : pkbf(0.0f, 1.0f), 0u, 0u, 0u);
    const s16x8 Bone = frag4(h ? 0u : pkbf(1.0f, 0.0f), 0u, 0u, 0u);

    for (int tile = (int)blockIdx.x; tile < NTILES; tile += P2GRID) {
        const int point = tile * 128 + wv * 32 + m;
        const int n = point >> 12;
        const float t = n * DT_F;
        const float y = y_ws[point];

        const s16x8 Bty = frag4(h ? 0u : pkbf(t, y), h ? 0u : pkbf(1.0f, 0.0f), 0u, 0u);

        f32x16 Cf0 = zf(), Cf1 = zf(), Ct0 = zf(), Ct1 = zf();
        {
            s16x8 A0 = frag_of(fragLDS[0 * 64 + l]);
            s16x8 A1 = frag_of(fragLDS[1 * 64 + l]);
            Cf0 = __builtin_amdgcn_mfma_f32_32x32x16_bf16(A0, Bty, Cf0, 0, 0, 0);
            Cf1 = __builtin_amdgcn_mfma_f32_32x32x16_bf16(A1, Bty, Cf1, 0, 0, 0);
            Ct0 = __builtin_amdgcn_mfma_f32_32x32x16_bf16(A0, Btn, Ct0, 0, 0, 0);
            Ct1 = __builtin_amdgcn_mfma_f32_32x32x16_bf16(A1, Btn, Ct1, 0, 0, 0);
        }
        s16x8 Bf[4], Bt[4];
        transition(Cf0, Cf1, Ct0, Ct1, h, Bf, Bt);

#pragma unroll
        for (int L = 0; L < 3; ++L) {
            Cf0 = zf(); Cf1 = zf(); Ct0 = zf(); Ct1 = zf();
#pragma unroll
            for (int b = 0; b < 4; ++b) {
                s16x8 A0 = frag_of(fragLDS[(2 + L * 10 + 0 + b) * 64 + l]);
                s16x8 A1 = frag_of(fragLDS[(2 + L * 10 + 5 + b) * 64 + l]);
                Cf0 = __builtin_amdgcn_mfma_f32_32x32x16_bf16(A0, Bf[b], Cf0, 0, 0, 0);
                Ct0 = __builtin_amdgcn_mfma_f32_32x32x16_bf16(A0, Bt[b], Ct0, 0, 0, 0);
                Cf1 = __builtin_amdgcn_mfma_f32_32x32x16_bf16(A1, Bf[b], Cf1, 0, 0, 0);
                Ct1 = __builtin_amdgcn_mfma_f32_32x32x16_bf16(A1, Bt[b], Ct1, 0, 0, 0);
            }
            {
                s16x8 Ab0 = frag_of(fragLDS[(2 + L * 10 + 0 + 4) * 64 + l]);
                s16x8 Ab1 = frag_of(fragLDS[(2 + L * 10 + 5 + 4) * 64 + l]);
                Cf0 = __builtin_amdgcn_mfma_f32_32x32x16_bf16(Ab0, Bone, Cf0, 0, 0, 0);
                Cf1 = __builtin_amdgcn_mfma_f32_32x32x16_bf16(Ab1, Bone, Cf1, 0, 0, 0);
            }
            transition(Cf0, Cf1, Ct0, Ct1, h, Bf, Bt);
        }

        f32x16 Cof = zf(), Cot = zf();
#pragma unroll
        for (int b = 0; b < 4; ++b) {
            s16x8 Ao = frag_of(fragLDS[(32 + b) * 64 + l]);
            Cof = __builtin_amdgcn_mfma_f32_32x32x16_bf16(Ao, Bf[b], Cof, 0, 0, 0);
            Cot = __builtin_amdgcn_mfma_f32_32x32x16_bf16(Ao, Bt[b], Cot, 0, 0, 0);
        }
        if (h == 0) {
            Y_ws[point]  = Cof[0] + bout;
            dY_ws[point] = Cot[0];
        }
    }
}

// ================= Phase 3: residuals + reduction =================

extern "C" __global__ void __launch_bounds__(256)
fbsnn_phase3(const float* __restrict__ y_ws, const float* __restrict__ q_ws,
             const float* __restrict__ Y_ws, const float* __restrict__ dY_ws,
             const float* __restrict__ dW, float* __restrict__ out)
{
    const int p = blockIdx.x * 256 + threadIdx.x;

    float Yc  = Y_ws[p];
    float acc = 0.0f;
#pragma unroll 5
    for (int n = 0; n < NSTEP; ++n) {
        float q    = q_ws[n * NPATH + p];
        float dYc  = dY_ws[n * NPATH + p];
        float dws  = dW[n * NPATH + p] * SQRT_DT;
        float Yn   = Y_ws[(n + 1) * NPATH + p];
        float Ytil = fmaf(-q * q, DT_F, Yc) + (SIGMA_F * dYc) * dws;
        float r    = Yn - Ytil;
        acc = fmaf(r, r, acc);
        Yc = Yn;
    }
    float y50  = y_ws[NSTEP * NPATH + p];
    float dY50 = dY_ws[NSTEP * NPATH + p];
    float r1 = Yc - y50 * y50;
    float r2 = dY50 - 2.0f * y50;
    acc = fmaf(r1, r1, fmaf(r2, r2, acc));

    float v = acc;
#pragma unroll
    for (int off = 32; off > 0; off >>= 1) v += __shfl_down(v, off, 64);
    if ((threadIdx.x & 63) == 0) atomicAdd(out, v * (1.0f / (float)NPATH));
}

// ================= host launch =================

extern "C" void kernel_launch(void* const* d_in, const int* in_sizes, int n_in,
                              void* d_out, int out_size, void* d_ws, size_t ws_size,
                              hipStream_t stream)
{
    const float* Y_Win  = (const float*)d_in[0];
    const float* Y_bin  = (const float*)d_in[1];
    const float* Y_Whid = (const float*)d_in[2];
    const float* Y_bhid = (const float*)d_in[3];
    const float* Y_Wout = (const float*)d_in[4];
    const float* Y_bout = (const float*)d_in[5];
    const float* q_Win  = (const float*)d_in[6];
    const float* q_bin  = (const float*)d_in[7];
    const float* q_Whid = (const float*)d_in[8];
    const float* q_bhid = (const float*)d_in[9];
    const float* q_Wout = (const float*)d_in[10];
    const float* q_bout = (const float*)d_in[11];
    const float* y0p    = (const float*)d_in[12];
    const float* dW     = (const float*)d_in[13];

    float* ws    = (float*)d_ws;
    float* y_ws  = ws;                          // 51*4096
    float* q_ws  = ws + 51 * NPATH;             // 50*4096
    float* Y_ws  = ws + 101 * NPATH;            // 51*4096
    float* dY_ws = ws + 152 * NPATH;            // 51*4096

    hipMemsetAsync(d_out, 0, sizeof(float), stream);

    fbsnn_phase1<<<dim3(128), dim3(64), 0, stream>>>(
        q_Win, q_bin, q_Whid, q_bhid, q_Wout, q_bout, y0p, dW, y_ws, q_ws);

    fbsnn_phase2<<<dim3(P2GRID), dim3(256), 0, stream>>>(
        Y_Win, Y_bin, Y_Whid, Y_bhid, Y_Wout, Y_bout, y_ws, Y_ws, dY_ws);

    fbsnn_phase3<<<dim3(NPATH / 256), dim3(256), 0, stream>>>(
        y_ws, q_ws, Y_ws, dY_ws, dW, (float*)d_out);
}